// Round 8
// baseline (213.276 us; speedup 1.0000x reference)
//
#include <hip/hip_runtime.h>

// Problem constants
#define BB   4
#define CC   144
#define HW   4096      // 64*64
#define PTOT 16384     // BB*HW
#define EPSB 1e-5f

typedef __bf16 bf16;
typedef __bf16 bf16x8 __attribute__((ext_vector_type(8)));
typedef float  f32x4  __attribute__((ext_vector_type(4)));
typedef unsigned short U16;
typedef unsigned int   U32;
typedef U16 u16x4 __attribute__((ext_vector_type(4)));
typedef U16 u16x8 __attribute__((ext_vector_type(8)));

#define MFMA __builtin_amdgcn_mfma_f32_16x16x32_bf16

// ---- workspace layout (bytes) ----
#define XN_OFF    0UL         // bf16 [16384][144] channel-last   4,718,592
#define A2_OFF    57147392UL  // bf16 [16384][9][64] (k=rs*64+c2) 18,874,368
#define WINF_OFF  76021760UL  // bf16 frag [4][5][64][8]          20,480
#define W1F_OFF   76042240UL  // bf16 frag [4][18][64][8]         73,728
#define W2F_OFF   76115968UL  // bf16 frag [4][18][64][8]         73,728
#define WOUTF_OFF 76189696UL  // bf16 frag [9][2][64][8]          18,432
#define BNP_OFF   76208128UL  // f32 [672]

// ------------------------------------------------------------------
// K1: L2 normalize over channel dim -> xn channel-last [p][144] bf16
__global__ __launch_bounds__(256) void k_norm(const float* __restrict__ x,
                                              bf16* __restrict__ xn)
{
    __shared__ float red[4][64];
    int bh = blockIdx.x;
    int b = bh >> 6, h = bh & 63;
    int t = threadIdx.x, w = t & 63, cq = t >> 6;
    const float* px = x + ((size_t)b*CC)*HW + h*64 + w;
    float vals[36];
    float s = 0.f;
    #pragma unroll
    for (int i = 0; i < 36; i++) { float v = px[(size_t)(cq*36 + i)*HW]; vals[i] = v; s += v*v; }
    red[cq][w] = s;
    __syncthreads();
    float tot = red[0][w] + red[1][w] + red[2][w] + red[3][w];
    float inv = 1.f / fmaxf(sqrtf(tot), 1e-12f);
    U16* po = (U16*)(xn + ((size_t)(bh*64 + w))*144 + cq*36);
    #pragma unroll
    for (int k = 0; k < 9; k++) {
        u16x4 pk;
        #pragma unroll
        for (int r = 0; r < 4; r++) { bf16 v = (bf16)(vals[k*4+r]*inv); pk[r] = *(U16*)&v; }
        *(u16x4*)(po + k*4) = pk;
    }
}

// ------------------------------------------------------------------
// K2: pack weights into MFMA A-fragment order + fold BN params
__global__ __launch_bounds__(256) void k_pack(
    const float* __restrict__ w_in, const float* __restrict__ w1,
    const float* __restrict__ w2,   const float* __restrict__ w_out,
    const float* g_in, const float* b_in, const float* m_in, const float* v_in,
    const float* g1,   const float* b1,   const float* m1,   const float* v1,
    const float* g2,   const float* b2,   const float* m2,   const float* v2,
    const float* g_out,const float* b_out,const float* m_out,const float* v_out,
    bf16* w_inf, bf16* w1f, bf16* w2f, bf16* w_outf, float* bnp)
{
    int t = blockIdx.x*256 + threadIdx.x;
    if (t < 10240) {                       // w_inf: k = c, padded 144->160
        int e = t, j = e & 7, lane = (e >> 3) & 63, r = e >> 9;
        int ks = r % 5, mt = r / 5;
        int o = mt*16 + (lane & 15);
        int c = ks*32 + ((lane >> 4) << 3) + j;
        w_inf[e] = (c < 144) ? (bf16)w_in[o*144 + c] : (bf16)0.f;
    } else if (t < 47104) {                // w1f: K=576, k = ij*64 + c
        int e = t - 10240, j = e & 7, lane = (e >> 3) & 63, r = e >> 9;
        int ks = r % 18, mt = r / 18;
        int o = mt*16 + (lane & 15);
        int k = ks*32 + ((lane >> 4) << 3) + j;
        int ij = k >> 6, c = k & 63;
        w1f[e] = (bf16)w1[(o*64 + c)*9 + ij];
    } else if (t < 83968) {                // w2f: k = rs*64 + c2 (matches a2 [p][rs][c2])
        int e = t - 47104, j = e & 7, lane = (e >> 3) & 63, r = e >> 9;
        int ks = r % 18, mt = r / 18;
        int o = mt*16 + (lane & 15);
        int k = ks*32 + ((lane >> 4) << 3) + j;
        int rs = k >> 6, c2 = k & 63;
        w2f[e] = (bf16)w2[o*576 + c2*9 + rs];
    } else if (t < 93184) {                // w_outf: M=144 (9 mt), K=64 (2 ks)
        int e = t - 83968, j = e & 7, lane = (e >> 3) & 63, r = e >> 9;
        int ks = r & 1, mt = r >> 1;
        int o = mt*16 + (lane & 15);
        int c = ks*32 + ((lane >> 4) << 3) + j;
        w_outf[e] = (bf16)w_out[o*64 + c];
    } else if (t < 93856) {                // BN fold
        int i = t - 93184;
        const float *g, *bb, *mm, *vv; int c; bool is_t;
        if (i < 128)      { g=g_in; bb=b_in; mm=m_in; vv=v_in; c=i&63;        is_t=i>=64;  }
        else if (i < 256) { g=g1;   bb=b1;   mm=m1;   vv=v1;   c=(i-128)&63;  is_t=i>=192; }
        else if (i < 384) { g=g2;   bb=b2;   mm=m2;   vv=v2;   c=(i-256)&63;  is_t=i>=320; }
        else              { int ii=i-384; g=g_out; bb=b_out; mm=m_out; vv=v_out;
                            c = ii % 144; is_t = ii >= 144; }
        float s = g[c] * rsqrtf(vv[c] + EPSB);
        bnp[i] = is_t ? (bb[c] - mm[c]*s) : s;
    }
}

// ------------------------------------------------------------------
// K3: FUSED stage1+stage2, rs-split. Block = 16 positions x ONE rs=(r,s).
// LDS: xn window W[3][18][152] (16.4KB, staged coalesced+zero-padded)
//      + a1 tile [16][9][64] XOR-swizzled (18.4KB). 4 blocks/CU.
// Stage1: waves split 9 ij (3/2/2/2): bfr from LDS window, MFMA, BN1+ReLU->a1t.
// Stage2: wave=mt: GEMM M=16,K=576,N=16 from a1t; BN2+ReLU -> a2[p][rs][c2].
#define WPITCH 152
__global__ __launch_bounds__(256) void k_s12(const bf16* __restrict__ xn,
        const bf16* __restrict__ w_inf, const bf16* __restrict__ w1f,
        const float* __restrict__ bnp, bf16* __restrict__ a2)
{
    __shared__ __align__(16) U16 Wn[3*18*WPITCH];  // 16416 B
    __shared__ __align__(16) U16 a1t[16*576];      // 18432 B
    int t = threadIdx.x;
    int wid = t >> 6, lane = t & 63, quad = lane >> 4, col16 = lane & 15;

    // XCD-affine work id: XCD x handles contiguous tiles, all 9 rs each
    int bb = blockIdx.x;
    int gwid = (bb & 7)*1152 + (bb >> 3);
    int tile = gwid / 9, rsid = gwid - 9*tile;
    int r = rsid / 3, s = rsid - 3*r;
    int p0 = tile*16;
    int b = p0 >> 12, h = (p0 >> 6) & 63, w0 = p0 & 63;

    // ---- stage xn window: rows h+r-2..h+r, cols w0+s-2..w0+s+15, zero-padded ----
    for (int i = t; i < 1026; i += 256) {          // 54 (rr,cc) x 19 chunks
        int cc_r = i / 19, k16 = i - 19*cc_r;
        int rr = cc_r / 18, cc = cc_r - 18*rr;
        u16x8 v = {};
        if (k16 < 18) {
            int hh = h + r - 2 + rr;
            int wg = w0 + s - 2 + cc;
            if ((unsigned)hh < 64u && (unsigned)wg < 64u) {
                const U16* src = (const U16*)(xn + ((size_t)(b*4096 + hh*64 + wg))*144);
                v = *(const u16x8*)(src + k16*8);
            }
        }
        *(u16x8*)&Wn[(rr*18 + cc)*WPITCH + k16*8] = v;
    }

    // BN1 params + center fragments
    f32x4 sv[4], tv[4];
    #pragma unroll
    for (int mt = 0; mt < 4; mt++) {
        sv[mt] = *(const f32x4*)&bnp[mt*16 + quad*4];
        tv[mt] = *(const f32x4*)&bnp[64 + mt*16 + quad*4];
    }
    __syncthreads();

    int rrc = 2 - r, ccc = col16 + 2 - s;
    bf16x8 cfr[5];
    #pragma unroll
    for (int ks = 0; ks < 5; ks++) {
        bf16x8 z = {};
        cfr[ks] = (ks < 4 || quad < 2)
            ? *(const bf16x8*)&Wn[(rrc*18 + ccc)*WPITCH + ks*32 + quad*8] : z;
    }

    // ---- stage 1: this block's 9 kp = (i+r, j+s), waves split ij 3/2/2/2 ----
    int nij = (wid == 0) ? 3 : 2;
    int ij0 = (wid == 0) ? 0 : (1 + wid*2);
    for (int u = 0; u < nij; u++) {
        int ij = ij0 + u;
        int i2 = ij / 3, j2 = ij - 3*i2;
        const U16* wrow = &Wn[(i2*18 + col16 + j2)*WPITCH];
        f32x4 acc[4] = {};
        #pragma unroll
        for (int ks = 0; ks < 5; ks++) {
            bf16x8 bfr = {};
            if (ks < 4 || quad < 2) {
                bf16x8 nv = *(const bf16x8*)(wrow + ks*32 + quad*8);
                #pragma unroll
                for (int j = 0; j < 8; j++)
                    bfr[j] = (bf16)((float)nv[j] * (float)cfr[ks][j]);
            }
            #pragma unroll
            for (int mt = 0; mt < 4; mt++) {
                bf16x8 af = *(const bf16x8*)(w_inf + ((mt*5 + ks)*64 + lane)*8);
                acc[mt] = MFMA(af, bfr, acc[mt], 0, 0, 0);
            }
        }
        #pragma unroll
        for (int mt = 0; mt < 4; mt++) {
            u16x4 pk;
            #pragma unroll
            for (int rr2 = 0; rr2 < 4; rr2++) {
                bf16 v = (bf16)fmaxf(acc[mt][rr2]*sv[mt][rr2] + tv[mt][rr2], 0.f);
                pk[rr2] = *(U16*)&v;
            }
            int grpW = (mt*2 + (quad >> 1)) ^ (col16 & 7);
            *(u16x4*)&a1t[col16*576 + ij*64 + grpW*8 + (quad & 1)*4] = pk;
        }
    }
    __syncthreads();

    // ---- stage 2: GEMM M=64 (wave=mt), K=576 (k=ij*64+c), N=16 ----
    f32x4 acc2 = {};
    #pragma unroll
    for (int ks = 0; ks < 18; ks++) {
        bf16x8 afr = *(const bf16x8*)(w1f + ((wid*18 + ks)*64 + lane)*8);
        int grpR = (((ks & 1)*4 + quad)) ^ (col16 & 7);
        bf16x8 bfr = *(const bf16x8*)&a1t[col16*576 + (ks >> 1)*64 + grpR*8];
        acc2 = MFMA(afr, bfr, acc2, 0, 0, 0);
    }
    int o = wid*16 + quad*4;
    f32x4 s2 = *(const f32x4*)&bnp[128 + o];
    f32x4 t2 = *(const f32x4*)&bnp[192 + o];
    u16x4 pk;
    #pragma unroll
    for (int rr2 = 0; rr2 < 4; rr2++) {
        bf16 v = (bf16)fmaxf(acc2[rr2]*s2[rr2] + t2[rr2], 0.f);
        pk[rr2] = *(U16*)&v;
    }
    *(u16x4*)(a2 + (size_t)(p0 + col16)*576 + rsid*64 + o) = pk;
}

// ------------------------------------------------------------------
// K4: stage 3 (64x576, 32 cols/block; a2 chunk staged to LDS swizzled)
//     + BN/ReLU -> swizzled v3 -> stage 4 (144x64) + final BN -> fp32 out.
__global__ __launch_bounds__(256) void k_s34(const bf16* __restrict__ a2,
        const bf16* __restrict__ w2f, const bf16* __restrict__ w_outf,
        const float* __restrict__ bnp, float* __restrict__ out)
{
    __shared__ __align__(16) U16 As[32*576];  // 36864 B
    __shared__ __align__(16) U16 v3[32*64];   // 4096 B
    int t = threadIdx.x, wid = t >> 6, lane = t & 63, quad = lane >> 4, col16 = lane & 15;
    int p0 = blockIdx.x * 32;
    int b = p0 >> 12, hw0 = p0 & 4095;

    const U16* gsrc = (const U16*)(a2 + (size_t)p0*576);
    u16x8 sreg[9];
    #pragma unroll
    for (int it = 0; it < 9; it++) sreg[it] = *(const u16x8*)(gsrc + (it*256 + t)*8);
    #pragma unroll
    for (int it = 0; it < 9; it++) {
        int i = it*256 + t;
        int c = i % 72, pr = i / 72;
        int dst = pr*576 + (c >> 3)*64 + ((((c & 7) + pr) & 7) << 3);
        *(u16x8*)&As[dst] = sreg[it];
    }
    bf16x8 aa[2];
    aa[0] = *(const bf16x8*)(w2f + ((wid*18)*64 + lane)*8);
    __syncthreads();

    f32x4 acc[2] = {};
    #pragma unroll
    for (int ks = 0; ks < 18; ks++) {
        if (ks + 1 < 18)
            aa[(ks+1) & 1] = *(const bf16x8*)(w2f + ((wid*18 + ks + 1)*64 + lane)*8);
        #pragma unroll
        for (int nt = 0; nt < 2; nt++) {
            int p = nt*16 + col16;
            int c = ks*4 + quad;
            int off = p*576 + (c >> 3)*64 + ((((c & 7) + p) & 7) << 3);
            bf16x8 bfr = *(const bf16x8*)&As[off];
            acc[nt] = MFMA(aa[ks & 1], bfr, acc[nt], 0, 0, 0);
        }
    }
    #pragma unroll
    for (int nt = 0; nt < 2; nt++) {
        int colA = nt*16 + col16;
        #pragma unroll
        for (int r = 0; r < 4; r++) {
            int o = wid*16 + quad*4 + r;
            float s = bnp[256 + o], tt = bnp[320 + o];
            bf16 yb = (bf16)fmaxf(acc[nt][r]*s + tt, 0.f);
            v3[colA*64 + (((o >> 3) + colA) & 7)*8 + (o & 7)] = *(U16*)&yb;
        }
    }
    __syncthreads();
    for (int mt = wid; mt < 9; mt += 4) {
        f32x4 accB[2] = {};
        #pragma unroll
        for (int ks = 0; ks < 2; ks++) {
            bf16x8 afr = *(const bf16x8*)(w_outf + ((mt*2 + ks)*64 + lane)*8);
            #pragma unroll
            for (int nt = 0; nt < 2; nt++) {
                int colA = nt*16 + col16;
                int g = ks*4 + quad;
                bf16x8 bfr = *(const bf16x8*)&v3[colA*64 + ((g + colA) & 7)*8];
                accB[nt] = MFMA(afr, bfr, accB[nt], 0, 0, 0);
            }
        }
        #pragma unroll
        for (int nt = 0; nt < 2; nt++) {
            #pragma unroll
            for (int r = 0; r < 4; r++) {
                int oc = mt*16 + quad*4 + r;
                float s = bnp[384 + oc], tt = bnp[528 + oc];
                out[((size_t)(b*144 + oc))*4096 + hw0 + nt*16 + col16] = accB[nt][r]*s + tt;
            }
        }
    }
}

// ------------------------------------------------------------------
extern "C" void kernel_launch(void* const* d_in, const int* in_sizes, int n_in,
                              void* d_out, int out_size, void* d_ws, size_t ws_size,
                              hipStream_t stream)
{
    const float* x     = (const float*)d_in[0];
    const float* w_in  = (const float*)d_in[1];
    const float* g_in  = (const float*)d_in[2];
    const float* b_in  = (const float*)d_in[3];
    const float* m_in  = (const float*)d_in[4];
    const float* v_in  = (const float*)d_in[5];
    const float* w1    = (const float*)d_in[6];
    const float* g1    = (const float*)d_in[7];
    const float* b1    = (const float*)d_in[8];
    const float* m1    = (const float*)d_in[9];
    const float* v1    = (const float*)d_in[10];
    const float* w2    = (const float*)d_in[11];
    const float* g2    = (const float*)d_in[12];
    const float* b2    = (const float*)d_in[13];
    const float* m2    = (const float*)d_in[14];
    const float* v2    = (const float*)d_in[15];
    const float* w_out = (const float*)d_in[16];
    const float* g_out = (const float*)d_in[17];
    const float* b_out = (const float*)d_in[18];
    const float* m_out = (const float*)d_in[19];
    const float* v_out = (const float*)d_in[20];
    float* out = (float*)d_out;

    char* ws = (char*)d_ws;
    bf16*  xn     = (bf16*)(ws + XN_OFF);
    bf16*  a2     = (bf16*)(ws + A2_OFF);
    bf16*  w_inf  = (bf16*)(ws + WINF_OFF);
    bf16*  w1f    = (bf16*)(ws + W1F_OFF);
    bf16*  w2f    = (bf16*)(ws + W2F_OFF);
    bf16*  w_outf = (bf16*)(ws + WOUTF_OFF);
    float* bnp    = (float*)(ws + BNP_OFF);

    hipLaunchKernelGGL(k_norm, dim3(256), dim3(256), 0, stream, x, xn);
    hipLaunchKernelGGL(k_pack, dim3(367), dim3(256), 0, stream,
                       w_in, w1, w2, w_out,
                       g_in, b_in, m_in, v_in, g1, b1, m1, v1,
                       g2, b2, m2, v2, g_out, b_out, m_out, v_out,
                       w_inf, w1f, w2f, w_outf, bnp);
    hipLaunchKernelGGL(k_s12, dim3(9216), dim3(256), 0, stream, xn, w_inf, w1f, bnp, a2);
    hipLaunchKernelGGL(k_s34, dim3(512), dim3(256), 0, stream, a2, w2f, w_outf, bnp, out);
}

// Round 9
// 176.738 us; speedup vs baseline: 1.2067x; 1.2067x over previous
//
#include <hip/hip_runtime.h>

// Problem constants
#define BB   4
#define CC   144
#define HW   4096      // 64*64
#define PTOT 16384     // BB*HW
#define EPSB 1e-5f

typedef __bf16 bf16;
typedef __bf16 bf16x8 __attribute__((ext_vector_type(8)));
typedef float  f32x4  __attribute__((ext_vector_type(4)));
typedef unsigned short U16;
typedef unsigned int   U32;
typedef U16 u16x4 __attribute__((ext_vector_type(4)));
typedef U16 u16x8 __attribute__((ext_vector_type(8)));

#define MFMA __builtin_amdgcn_mfma_f32_16x16x32_bf16

// ---- workspace layout (bytes) ----
#define XN_OFF    0UL         // bf16 [16384][144] channel-last   4,718,592
#define WINF_OFF  76021760UL  // bf16 frag [4][5][64][8]          20,480
#define W1F_OFF   76042240UL  // bf16 frag [4][18][64][8]         73,728
#define W2F_OFF   76115968UL  // bf16 frag [4][18][64][8]         73,728
#define WOUTF_OFF 76189696UL  // bf16 frag [9][2][64][8]          18,432
#define BNP_OFF   76208128UL  // f32 [672]

// ------------------------------------------------------------------
// K1: L2 normalize over channel dim -> xn channel-last [p][144] bf16
__global__ __launch_bounds__(256) void k_norm(const float* __restrict__ x,
                                              bf16* __restrict__ xn)
{
    __shared__ float red[4][64];
    int bh = blockIdx.x;
    int b = bh >> 6, h = bh & 63;
    int t = threadIdx.x, w = t & 63, cq = t >> 6;
    const float* px = x + ((size_t)b*CC)*HW + h*64 + w;
    float vals[36];
    float s = 0.f;
    #pragma unroll
    for (int i = 0; i < 36; i++) { float v = px[(size_t)(cq*36 + i)*HW]; vals[i] = v; s += v*v; }
    red[cq][w] = s;
    __syncthreads();
    float tot = red[0][w] + red[1][w] + red[2][w] + red[3][w];
    float inv = 1.f / fmaxf(sqrtf(tot), 1e-12f);
    U16* po = (U16*)(xn + ((size_t)(bh*64 + w))*144 + cq*36);
    #pragma unroll
    for (int k = 0; k < 9; k++) {
        u16x4 pk;
        #pragma unroll
        for (int r = 0; r < 4; r++) { bf16 v = (bf16)(vals[k*4+r]*inv); pk[r] = *(U16*)&v; }
        *(u16x4*)(po + k*4) = pk;
    }
}

// ------------------------------------------------------------------
// K2: pack weights into MFMA A-fragment order + fold BN params
__global__ __launch_bounds__(256) void k_pack(
    const float* __restrict__ w_in, const float* __restrict__ w1,
    const float* __restrict__ w2,   const float* __restrict__ w_out,
    const float* g_in, const float* b_in, const float* m_in, const float* v_in,
    const float* g1,   const float* b1,   const float* m1,   const float* v1,
    const float* g2,   const float* b2,   const float* m2,   const float* v2,
    const float* g_out,const float* b_out,const float* m_out,const float* v_out,
    bf16* w_inf, bf16* w1f, bf16* w2f, bf16* w_outf, float* bnp)
{
    int t = blockIdx.x*256 + threadIdx.x;
    if (t < 10240) {                       // w_inf: k = c, padded 144->160
        int e = t, j = e & 7, lane = (e >> 3) & 63, r = e >> 9;
        int ks = r % 5, mt = r / 5;
        int o = mt*16 + (lane & 15);
        int c = ks*32 + ((lane >> 4) << 3) + j;
        w_inf[e] = (c < 144) ? (bf16)w_in[o*144 + c] : (bf16)0.f;
    } else if (t < 47104) {                // w1f: K=576, k = ij*64 + c
        int e = t - 10240, j = e & 7, lane = (e >> 3) & 63, r = e >> 9;
        int ks = r % 18, mt = r / 18;
        int o = mt*16 + (lane & 15);
        int k = ks*32 + ((lane >> 4) << 3) + j;
        int ij = k >> 6, c = k & 63;
        w1f[e] = (bf16)w1[(o*64 + c)*9 + ij];
    } else if (t < 83968) {                // w2f: k = rs*64 + c2
        int e = t - 47104, j = e & 7, lane = (e >> 3) & 63, r = e >> 9;
        int ks = r % 18, mt = r / 18;
        int o = mt*16 + (lane & 15);
        int k = ks*32 + ((lane >> 4) << 3) + j;
        int rs = k >> 6, c2 = k & 63;
        w2f[e] = (bf16)w2[o*576 + c2*9 + rs];
    } else if (t < 93184) {                // w_outf: M=144 (9 mt), K=64 (2 ks)
        int e = t - 83968, j = e & 7, lane = (e >> 3) & 63, r = e >> 9;
        int ks = r & 1, mt = r >> 1;
        int o = mt*16 + (lane & 15);
        int c = ks*32 + ((lane >> 4) << 3) + j;
        w_outf[e] = (bf16)w_out[o*64 + c];
    } else if (t < 93856) {                // BN fold
        int i = t - 93184;
        const float *g, *bb, *mm, *vv; int c; bool is_t;
        if (i < 128)      { g=g_in; bb=b_in; mm=m_in; vv=v_in; c=i&63;        is_t=i>=64;  }
        else if (i < 256) { g=g1;   bb=b1;   mm=m1;   vv=v1;   c=(i-128)&63;  is_t=i>=192; }
        else if (i < 384) { g=g2;   bb=b2;   mm=m2;   vv=v2;   c=(i-256)&63;  is_t=i>=320; }
        else              { int ii=i-384; g=g_out; bb=b_out; mm=m_out; vv=v_out;
                            c = ii % 144; is_t = ii >= 144; }
        float s = g[c] * rsqrtf(vv[c] + EPSB);
        bnp[i] = is_t ? (bb[c] - mm[c]*s) : s;
    }
}

// ------------------------------------------------------------------
// K3: FULLY FUSED stages 1-4. Block = 16 positions -> final output.
// LDS: uni = union{ Wn[3][20][152] (18.2KB) | a2t[16][9][64]+v3t[16][64] (20.5KB) }
//    + a1t[16][25][64] swizzled (51.2KB). Peak 71.7KB -> 2 blocks/CU.
// Phases: stage rows{2,0,1} | s1 kp 0-14 | stage rows{3,4} | s1 kp 15-24 |
//         s2 (rs-split) -> a2t | s3 (wave=cm-tile) -> v3t | s4 -> out.
__global__ __launch_bounds__(256) void k_f(const bf16* __restrict__ xn,
        const bf16* __restrict__ w_inf, const bf16* __restrict__ w1f,
        const bf16* __restrict__ w2f,   const bf16* __restrict__ w_outf,
        const float* __restrict__ bnp,  float* __restrict__ out)
{
    __shared__ __align__(16) U16 uni[10240];   // 20480 B (Wn uses 9120 els)
    __shared__ __align__(16) U16 a1t[25600];   // 51200 B
    int t = threadIdx.x;
    int wid = t >> 6, lane = t & 63, quad = lane >> 4, col = lane & 15;
    int bb = blockIdx.x;
    int tile = (bb & 7)*128 + (bb >> 3);       // XCD-contiguous tile ranges
    int p0 = tile*16;
    int b = p0 >> 12, h = (p0 >> 6) & 63, w0 = p0 & 63;
    const int LUT5[9] = {0,1,2,5,6,7,10,11,12};

    // ---- phase 0: stage window rows {2,0,1} -> slots {0,1,2} ----
    for (int idx = t; idx < 1080; idx += 256) {
        int k16 = idx % 18, cr = idx / 18;
        int sl = cr / 20, cc = cr % 20;
        int i_row = (sl == 0) ? 2 : (sl - 1);
        int hh = h + i_row - 2;
        int wg = w0 + cc - 2;
        u16x8 v = {};
        if ((unsigned)hh < 64u && (unsigned)wg < 64u)
            v = *(const u16x8*)((const U16*)(xn + ((size_t)(b*4096 + hh*64 + wg))*144) + k16*8);
        *(u16x8*)&uni[(sl*20 + cc)*152 + k16*8] = v;
    }
    // A-frags + BN1 while staging is in flight
    bf16x8 af[4][5];
    #pragma unroll
    for (int mt = 0; mt < 4; mt++)
        #pragma unroll
        for (int ks = 0; ks < 5; ks++)
            af[mt][ks] = *(const bf16x8*)(w_inf + ((mt*5 + ks)*64 + lane)*8);
    f32x4 sv1[4], tv1[4];
    #pragma unroll
    for (int mt = 0; mt < 4; mt++) {
        sv1[mt] = *(const f32x4*)&bnp[mt*16 + quad*4];
        tv1[mt] = *(const f32x4*)&bnp[64 + mt*16 + quad*4];
    }
    __syncthreads();

    // center fragments (slot 0, window col = col+2)
    bf16x8 cfr[5];
    #pragma unroll
    for (int ks = 0; ks < 5; ks++) {
        bf16x8 z = {};
        cfr[ks] = (ks < 4 || quad < 2)
            ? *(const bf16x8*)&uni[(col + 2)*152 + ks*32 + quad*8] : z;
    }

    auto do_kp = [&](int kp, int sl, int j2) {
        const U16* wrow = &uni[(sl*20 + col + j2)*152];
        f32x4 acc[4] = {};
        #pragma unroll
        for (int ks = 0; ks < 5; ks++) {
            bf16x8 bfr = {};
            if (ks < 4 || quad < 2) {
                bf16x8 nv = *(const bf16x8*)(wrow + ks*32 + quad*8);
                #pragma unroll
                for (int j = 0; j < 8; j++)
                    bfr[j] = (bf16)((float)nv[j] * (float)cfr[ks][j]);
            }
            #pragma unroll
            for (int mt = 0; mt < 4; mt++)
                acc[mt] = MFMA(af[mt][ks], bfr, acc[mt], 0, 0, 0);
        }
        #pragma unroll
        for (int mt = 0; mt < 4; mt++) {
            u16x4 pk;
            #pragma unroll
            for (int r = 0; r < 4; r++) {
                bf16 v = (bf16)fmaxf(acc[mt][r]*sv1[mt][r] + tv1[mt][r], 0.f);
                pk[r] = *(U16*)&v;
            }
            int grp = ((mt*2 + (quad >> 1)) + kp*3 + col) & 7;
            *(u16x4*)&a1t[col*1600 + kp*64 + grp*8 + (quad & 1)*4] = pk;
        }
    };

    // ---- phase 1: kp 0..14 (rows 0,1,2), split 4/4/4/3 ----
    for (int kp = wid; kp < 15; kp += 4) {
        int i = kp / 5, j2 = kp - 5*i;
        do_kp(kp, (i == 2) ? 0 : (i + 1), j2);
    }
    __syncthreads();

    // ---- phase 2: stage rows {3,4} -> slots {1,2} ----
    for (int idx = t; idx < 720; idx += 256) {
        int k16 = idx % 18, cr = idx / 18;
        int sl = 1 + cr / 20, cc = cr % 20;
        int hh = h + sl;                      // slot1 -> h+1, slot2 -> h+2
        int wg = w0 + cc - 2;
        u16x8 v = {};
        if ((unsigned)hh < 64u && (unsigned)wg < 64u)
            v = *(const u16x8*)((const U16*)(xn + ((size_t)(b*4096 + hh*64 + wg))*144) + k16*8);
        *(u16x8*)&uni[(sl*20 + cc)*152 + k16*8] = v;
    }
    __syncthreads();

    // ---- phase 3: kp 15..24 (rows 3,4), split 3/3/2/2 ----
    for (int kp = 15 + wid; kp < 25; kp += 4) {
        int i = kp / 5, j2 = kp - 5*i;
        do_kp(kp, i - 2, j2);
    }
    __syncthreads();

    // ---- phase 4: stage 2 (rs-split 3/2/2/2) -> a2t (in uni, Wn dead) ----
    U16* a2t = uni;
    U16* v3t = &uni[9216];
    const int rsbase[4] = {0,3,5,7};
    int rs0 = rsbase[wid], nrs = (wid == 0) ? 3 : 2;
    f32x4 acc2[3][4] = {};
    #pragma unroll
    for (int ks2 = 0; ks2 < 18; ks2++) {
        int ij = ks2 >> 1;
        bf16x8 afr[4];
        #pragma unroll
        for (int mt = 0; mt < 4; mt++)
            afr[mt] = *(const bf16x8*)(w1f + ((mt*18 + ks2)*64 + lane)*8);
        #pragma unroll
        for (int u = 0; u < 3; u++) {
            if (u < nrs) {
                int kp = LUT5[ij] + LUT5[rs0 + u];
                int grp = (((ks2 & 1)*4 + quad) + kp*3 + col) & 7;
                bf16x8 bfr = *(const bf16x8*)&a1t[col*1600 + kp*64 + grp*8];
                #pragma unroll
                for (int mt = 0; mt < 4; mt++)
                    acc2[u][mt] = MFMA(afr[mt], bfr, acc2[u][mt], 0, 0, 0);
            }
        }
    }
    #pragma unroll
    for (int u = 0; u < 3; u++) {
        if (u < nrs) {
            int rsid = rs0 + u;
            #pragma unroll
            for (int mt = 0; mt < 4; mt++) {
                int c2b = mt*16 + quad*4;
                f32x4 s = *(const f32x4*)&bnp[128 + c2b];
                f32x4 tt = *(const f32x4*)&bnp[192 + c2b];
                u16x4 pk;
                #pragma unroll
                for (int r = 0; r < 4; r++) {
                    bf16 v = (bf16)fmaxf(acc2[u][mt][r]*s[r] + tt[r], 0.f);
                    pk[r] = *(U16*)&v;
                }
                int g = ((mt*2 + (quad >> 1)) + rsid + col) & 7;
                *(u16x4*)&a2t[col*576 + rsid*64 + g*8 + (quad & 1)*4] = pk;
            }
        }
    }
    __syncthreads();

    // ---- phase 5: stage 3 (wave = cm-tile), K = rsid*64+c2 ----
    f32x4 acc3 = {};
    #pragma unroll
    for (int ks3 = 0; ks3 < 18; ks3++) {
        bf16x8 afr = *(const bf16x8*)(w2f + ((wid*18 + ks3)*64 + lane)*8);
        int rsid = ks3 >> 1;
        int g = (((ks3 & 1)*4 + quad) + rsid + col) & 7;
        bf16x8 bfr = *(const bf16x8*)&a2t[col*576 + rsid*64 + g*8];
        acc3 = MFMA(afr, bfr, acc3, 0, 0, 0);
    }
    {
        int cmb = wid*16 + quad*4;
        f32x4 s = *(const f32x4*)&bnp[256 + cmb];
        f32x4 tt = *(const f32x4*)&bnp[320 + cmb];
        u16x4 pk;
        #pragma unroll
        for (int r = 0; r < 4; r++) {
            bf16 v = (bf16)fmaxf(acc3[r]*s[r] + tt[r], 0.f);
            pk[r] = *(U16*)&v;
        }
        int gv = ((wid*2 + (quad >> 1)) + col) & 7;
        *(u16x4*)&v3t[col*64 + gv*8 + (quad & 1)*4] = pk;
    }
    __syncthreads();

    // ---- phase 6: stage 4 (M=144 over waves 3/2/2/2), final BN -> fp32 out ----
    int hw0 = h*64 + w0;
    for (int mt4 = wid; mt4 < 9; mt4 += 4) {
        f32x4 acc4 = {};
        #pragma unroll
        for (int ks4 = 0; ks4 < 2; ks4++) {
            bf16x8 afr = *(const bf16x8*)(w_outf + ((mt4*2 + ks4)*64 + lane)*8);
            int gv = ((ks4*4 + quad) + col) & 7;
            bf16x8 bfr = *(const bf16x8*)&v3t[col*64 + gv*8];
            acc4 = MFMA(afr, bfr, acc4, 0, 0, 0);
        }
        #pragma unroll
        for (int r = 0; r < 4; r++) {
            int oc = mt4*16 + quad*4 + r;
            out[((size_t)(b*144 + oc))*4096 + hw0 + col] = acc4[r]*bnp[384 + oc] + bnp[528 + oc];
        }
    }
}

// ------------------------------------------------------------------
extern "C" void kernel_launch(void* const* d_in, const int* in_sizes, int n_in,
                              void* d_out, int out_size, void* d_ws, size_t ws_size,
                              hipStream_t stream)
{
    const float* x     = (const float*)d_in[0];
    const float* w_in  = (const float*)d_in[1];
    const float* g_in  = (const float*)d_in[2];
    const float* b_in  = (const float*)d_in[3];
    const float* m_in  = (const float*)d_in[4];
    const float* v_in  = (const float*)d_in[5];
    const float* w1    = (const float*)d_in[6];
    const float* g1    = (const float*)d_in[7];
    const float* b1    = (const float*)d_in[8];
    const float* m1    = (const float*)d_in[9];
    const float* v1    = (const float*)d_in[10];
    const float* w2    = (const float*)d_in[11];
    const float* g2    = (const float*)d_in[12];
    const float* b2    = (const float*)d_in[13];
    const float* m2    = (const float*)d_in[14];
    const float* v2    = (const float*)d_in[15];
    const float* w_out = (const float*)d_in[16];
    const float* g_out = (const float*)d_in[17];
    const float* b_out = (const float*)d_in[18];
    const float* m_out = (const float*)d_in[19];
    const float* v_out = (const float*)d_in[20];
    float* out = (float*)d_out;

    char* ws = (char*)d_ws;
    bf16*  xn     = (bf16*)(ws + XN_OFF);
    bf16*  w_inf  = (bf16*)(ws + WINF_OFF);
    bf16*  w1f    = (bf16*)(ws + W1F_OFF);
    bf16*  w2f    = (bf16*)(ws + W2F_OFF);
    bf16*  w_outf = (bf16*)(ws + WOUTF_OFF);
    float* bnp    = (float*)(ws + BNP_OFF);

    hipLaunchKernelGGL(k_norm, dim3(256), dim3(256), 0, stream, x, xn);
    hipLaunchKernelGGL(k_pack, dim3(367), dim3(256), 0, stream,
                       w_in, w1, w2, w_out,
                       g_in, b_in, m_in, v_in, g1, b1, m1, v1,
                       g2, b2, m2, v2, g_out, b_out, m_out, v_out,
                       w_inf, w1f, w2f, w_outf, bnp);
    hipLaunchKernelGGL(k_f, dim3(1024), dim3(256), 0, stream,
                       xn, w_inf, w1f, w2f, w_outf, bnp, out);
}

// Round 10
// 175.909 us; speedup vs baseline: 1.2124x; 1.0047x over previous
//
#include <hip/hip_runtime.h>

// Problem constants
#define BB   4
#define CC   144
#define HW   4096      // 64*64
#define PTOT 16384     // BB*HW
#define EPSB 1e-5f

typedef __bf16 bf16;
typedef __bf16 bf16x8 __attribute__((ext_vector_type(8)));
typedef float  f32x4  __attribute__((ext_vector_type(4)));
typedef unsigned short U16;
typedef unsigned int   U32;
typedef U16 u16x4 __attribute__((ext_vector_type(4)));
typedef U16 u16x8 __attribute__((ext_vector_type(8)));

#define MFMA __builtin_amdgcn_mfma_f32_16x16x32_bf16

// ---- workspace layout (bytes) ----
#define XN_OFF    0UL         // bf16 [16384][144] channel-last   4,718,592
#define A1_OFF    4718592UL   // bf16 [16384][25][64]             52,428,800
#define WINF_OFF  76021760UL  // bf16 frag [4][5][64][8]          20,480
#define W1F_OFF   76042240UL  // bf16 frag [4][18][64][8]         73,728
#define W2F_OFF   76115968UL  // bf16 frag [4][18][64][8]         73,728
#define WOUTF_OFF 76189696UL  // bf16 frag [9][2][64][8]          18,432
#define BNP_OFF   76208128UL  // f32 [672]

// ------------------------------------------------------------------
// K1: L2 normalize over channel dim -> xn channel-last [p][144] bf16
__global__ __launch_bounds__(256) void k_norm(const float* __restrict__ x,
                                              bf16* __restrict__ xn)
{
    __shared__ float red[4][64];
    int bh = blockIdx.x;
    int b = bh >> 6, h = bh & 63;
    int t = threadIdx.x, w = t & 63, cq = t >> 6;
    const float* px = x + ((size_t)b*CC)*HW + h*64 + w;
    float vals[36];
    float s = 0.f;
    #pragma unroll
    for (int i = 0; i < 36; i++) { float v = px[(size_t)(cq*36 + i)*HW]; vals[i] = v; s += v*v; }
    red[cq][w] = s;
    __syncthreads();
    float tot = red[0][w] + red[1][w] + red[2][w] + red[3][w];
    float inv = 1.f / fmaxf(sqrtf(tot), 1e-12f);
    U16* po = (U16*)(xn + ((size_t)(bh*64 + w))*144 + cq*36);
    #pragma unroll
    for (int k = 0; k < 9; k++) {
        u16x4 pk;
        #pragma unroll
        for (int r = 0; r < 4; r++) { bf16 v = (bf16)(vals[k*4+r]*inv); pk[r] = *(U16*)&v; }
        *(u16x4*)(po + k*4) = pk;
    }
}

// ------------------------------------------------------------------
// K2: pack weights into MFMA A-fragment order + fold BN params
__global__ __launch_bounds__(256) void k_pack(
    const float* __restrict__ w_in, const float* __restrict__ w1,
    const float* __restrict__ w2,   const float* __restrict__ w_out,
    const float* g_in, const float* b_in, const float* m_in, const float* v_in,
    const float* g1,   const float* b1,   const float* m1,   const float* v1,
    const float* g2,   const float* b2,   const float* m2,   const float* v2,
    const float* g_out,const float* b_out,const float* m_out,const float* v_out,
    bf16* w_inf, bf16* w1f, bf16* w2f, bf16* w_outf, float* bnp)
{
    int t = blockIdx.x*256 + threadIdx.x;
    if (t < 10240) {                       // w_inf: k = c, padded 144->160
        int e = t, j = e & 7, lane = (e >> 3) & 63, r = e >> 9;
        int ks = r % 5, mt = r / 5;
        int o = mt*16 + (lane & 15);
        int c = ks*32 + ((lane >> 4) << 3) + j;
        w_inf[e] = (c < 144) ? (bf16)w_in[o*144 + c] : (bf16)0.f;
    } else if (t < 47104) {                // w1f: K=576, k = ij*64 + c
        int e = t - 10240, j = e & 7, lane = (e >> 3) & 63, r = e >> 9;
        int ks = r % 18, mt = r / 18;
        int o = mt*16 + (lane & 15);
        int k = ks*32 + ((lane >> 4) << 3) + j;
        int ij = k >> 6, c = k & 63;
        w1f[e] = (bf16)w1[(o*64 + c)*9 + ij];
    } else if (t < 83968) {                // w2f: k = rs*64 + c2
        int e = t - 47104, j = e & 7, lane = (e >> 3) & 63, r = e >> 9;
        int ks = r % 18, mt = r / 18;
        int o = mt*16 + (lane & 15);
        int k = ks*32 + ((lane >> 4) << 3) + j;
        int rs = k >> 6, c2 = k & 63;
        w2f[e] = (bf16)w2[o*576 + c2*9 + rs];
    } else if (t < 93184) {                // w_outf: M=144 (9 mt), K=64 (2 ks)
        int e = t - 83968, j = e & 7, lane = (e >> 3) & 63, r = e >> 9;
        int ks = r & 1, mt = r >> 1;
        int o = mt*16 + (lane & 15);
        int c = ks*32 + ((lane >> 4) << 3) + j;
        w_outf[e] = (bf16)w_out[o*64 + c];
    } else if (t < 93856) {                // BN fold
        int i = t - 93184;
        const float *g, *bb, *mm, *vv; int c; bool is_t;
        if (i < 128)      { g=g_in; bb=b_in; mm=m_in; vv=v_in; c=i&63;        is_t=i>=64;  }
        else if (i < 256) { g=g1;   bb=b1;   mm=m1;   vv=v1;   c=(i-128)&63;  is_t=i>=192; }
        else if (i < 384) { g=g2;   bb=b2;   mm=m2;   vv=v2;   c=(i-256)&63;  is_t=i>=320; }
        else              { int ii=i-384; g=g_out; bb=b_out; mm=m_out; vv=v_out;
                            c = ii % 144; is_t = ii >= 144; }
        float s = g[c] * rsqrtf(vv[c] + EPSB);
        bnp[i] = is_t ? (bb[c] - mm[c]*s) : s;
    }
}

// ------------------------------------------------------------------
// K3: stage 1 (R6 proven). Block = one image row x one dh (kpg).
#define LROW 168
__global__ __launch_bounds__(256) void k_s1(const bf16* __restrict__ xn,
        const bf16* __restrict__ w_inf, const float* __restrict__ bnp,
        bf16* __restrict__ a1)
{
    __shared__ __align__(16) U16 nb[68*LROW];   // 22848 B
    int t = threadIdx.x;
    int wid = t >> 6, lane = t & 63, quad = lane >> 4, col16 = lane & 15;
    int tile = blockIdx.x & 255, kpg = blockIdx.x >> 8;
    int dh = kpg - 2;
    int h = tile & 63;
    int p = tile*64 + wid*16 + col16;
    int w = p & 63;
    const bf16* xrow = xn + (size_t)p*144;

    int hr = h + dh;
    u16x8 z = {};
    if ((unsigned)hr < 64u) {
        for (int i = t; i < 84; i += 256) {
            int r = i / 21, cc = i % 21;
            int row = (r < 2) ? r : 64 + r;
            *(u16x8*)&nb[row*LROW + cc*8] = z;
        }
        for (int i = t; i < 192; i += 256) {
            int row = 2 + i / 3, cc = 18 + (i % 3);
            *(u16x8*)&nb[row*LROW + cc*8] = z;
        }
        const U16* grow = (const U16*)(xn + ((size_t)(tile + dh) * 64) * 144);
        for (int i = t; i < 1152; i += 256) {
            int wcol = i / 18, k16 = i - 18*wcol;
            u16x8 v = *(const u16x8*)(grow + wcol*144 + k16*8);
            *(u16x8*)&nb[(2 + wcol)*LROW + k16*8] = v;
        }
    } else {
        for (int i = t; i < 68*LROW/8; i += 256) *(u16x8*)&nb[i*8] = z;
    }
    bf16x8 af[4][5];
    #pragma unroll
    for (int mt = 0; mt < 4; mt++)
        #pragma unroll
        for (int ks = 0; ks < 5; ks++)
            af[mt][ks] = *(const bf16x8*)(w_inf + ((mt*5 + ks)*64 + lane)*8);
    bf16x8 cfr[5];
    #pragma unroll
    for (int ks = 0; ks < 5; ks++) {
        bf16x8 zz = {};
        cfr[ks] = (ks < 4 || quad < 2) ? *(const bf16x8*)(xrow + ks*32 + quad*8) : zz;
    }
    f32x4 sv[4], tv[4];
    #pragma unroll
    for (int mt = 0; mt < 4; mt++) {
        sv[mt] = *(const f32x4*)&bnp[mt*16 + quad*4];
        tv[mt] = *(const f32x4*)&bnp[64 + mt*16 + quad*4];
    }
    __syncthreads();

    for (int kpl = 0; kpl < 5; kpl++) {
        const bf16* lrow = (const bf16*)&nb[(w + kpl)*LROW];
        f32x4 acc[4] = {};
        #pragma unroll
        for (int ks = 0; ks < 5; ks++) {
            bf16x8 nv = *(const bf16x8*)(lrow + ks*32 + quad*8);
            bf16x8 bfr;
            #pragma unroll
            for (int j = 0; j < 8; j++)
                bfr[j] = (bf16)((float)nv[j] * (float)cfr[ks][j]);
            #pragma unroll
            for (int mt = 0; mt < 4; mt++)
                acc[mt] = MFMA(af[mt][ks], bfr, acc[mt], 0, 0, 0);
        }
        int kp = kpg*5 + kpl;
        bf16* arow = a1 + (size_t)p*1600 + kp*64;
        #pragma unroll
        for (int mt = 0; mt < 4; mt++) {
            u16x4 pk;
            #pragma unroll
            for (int r = 0; r < 4; r++) {
                bf16 v = (bf16)fmaxf(acc[mt][r]*sv[mt][r] + tv[mt][r], 0.f);
                pk[r] = *(U16*)&v;
            }
            *(u16x4*)(arow + mt*16 + quad*4) = pk;
        }
    }
}

// ------------------------------------------------------------------
// K4: FUSED stages 2+3+4. Block = 16 positions.
// Phase A: stage a1[16 pos] (51.2KB) -> LDS, R6 swizzle.
// Phase B: stage 2, waves split rs 3/2/2/2, acc in regs.
// Phase C: overlay a2t[16][9][64]+v3t[16][64] into dead a1t space;
//          BN2+ReLU -> a2t; s3 (wave=cm-tile) -> v3t; s4 -> fp32 out.
// Peak LDS 51.2KB -> 3 blocks/CU. grid 1024.
__global__ __launch_bounds__(256) void k_s234(const bf16* __restrict__ a1,
        const bf16* __restrict__ w1f, const bf16* __restrict__ w2f,
        const bf16* __restrict__ w_outf, const float* __restrict__ bnp,
        float* __restrict__ out)
{
    __shared__ __align__(16) U16 a1t[25600];   // 51200 B
    int t = threadIdx.x;
    int wid = t >> 6, lane = t & 63, quad = lane >> 4, col = lane & 15;
    const int LUT5[9] = {0,1,2,5,6,7,10,11,12};
    int bb = blockIdx.x;
    int tile = (bb & 7)*128 + (bb >> 3);       // XCD-contiguous tile ranges
    int p0 = tile*16;
    int b = p0 >> 12, hw0 = p0 & 4095;

    // ---- phase A: stage 16 a1 rows (contiguous 51200 B), R6 swizzle ----
    const U16* gsrc = (const U16*)(a1 + (size_t)p0*1600);
    u16x8 sreg[13];
    #pragma unroll
    for (int it = 0; it < 13; it++) {
        int i = it*256 + t;
        if (i < 3200) sreg[it] = *(const u16x8*)(gsrc + i*8);
    }
    #pragma unroll
    for (int it = 0; it < 13; it++) {
        int i = it*256 + t;
        if (i < 3200) {
            int grp = i & 7, rem = i >> 3;
            int kpidx = rem % 25, prow = rem / 25;
            int dst = prow*1600 + kpidx*64 + (((grp + kpidx*3 + prow*4) & 7) << 3);
            *(u16x8*)&a1t[dst] = sreg[it];
        }
    }
    __syncthreads();

    // ---- phase B: stage 2, waves split rs {3,2,2,2} ----
    const int rsbase[4] = {0,3,5,7};
    int rs0 = rsbase[wid], nrs = (wid == 0) ? 3 : 2;
    f32x4 acc2[3][4] = {};
    #pragma unroll
    for (int ks2 = 0; ks2 < 18; ks2++) {
        int ij = ks2 >> 1, half = ks2 & 1;
        bf16x8 afr[4];
        #pragma unroll
        for (int mt = 0; mt < 4; mt++)
            afr[mt] = *(const bf16x8*)(w1f + ((mt*18 + ks2)*64 + lane)*8);
        #pragma unroll
        for (int u = 0; u < 3; u++) {
            if (u < nrs) {
                int kp = LUT5[ij] + LUT5[rs0 + u];
                int off = col*1600 + kp*64 + ((((half*4 + quad) + kp*3 + col*4) & 7) << 3);
                bf16x8 bfr = *(const bf16x8*)&a1t[off];
                #pragma unroll
                for (int mt = 0; mt < 4; mt++)
                    acc2[u][mt] = MFMA(afr[mt], bfr, acc2[u][mt], 0, 0, 0);
            }
        }
    }
    __syncthreads();                            // a1t dead after this

    // ---- phase C1: BN2+ReLU -> a2t (overlaid on a1t) ----
    U16* a2t = a1t;
    U16* v3t = &a1t[9216];
    #pragma unroll
    for (int u = 0; u < 3; u++) {
        if (u < nrs) {
            int rsid = rs0 + u;
            #pragma unroll
            for (int mt = 0; mt < 4; mt++) {
                int c2b = mt*16 + quad*4;
                f32x4 s = *(const f32x4*)&bnp[128 + c2b];
                f32x4 tt = *(const f32x4*)&bnp[192 + c2b];
                u16x4 pk;
                #pragma unroll
                for (int r = 0; r < 4; r++) {
                    bf16 v = (bf16)fmaxf(acc2[u][mt][r]*s[r] + tt[r], 0.f);
                    pk[r] = *(U16*)&v;
                }
                int g = ((mt*2 + (quad >> 1)) + rsid + col) & 7;
                *(u16x4*)&a2t[col*576 + rsid*64 + g*8 + (quad & 1)*4] = pk;
            }
        }
    }
    __syncthreads();

    // ---- phase C2: stage 3 (wave = cm-tile), K = rs*64+c2 ----
    f32x4 acc3 = {};
    #pragma unroll
    for (int ks3 = 0; ks3 < 18; ks3++) {
        bf16x8 afr = *(const bf16x8*)(w2f + ((wid*18 + ks3)*64 + lane)*8);
        int rsid = ks3 >> 1;
        int g = (((ks3 & 1)*4 + quad) + rsid + col) & 7;
        bf16x8 bfr = *(const bf16x8*)&a2t[col*576 + rsid*64 + g*8];
        acc3 = MFMA(afr, bfr, acc3, 0, 0, 0);
    }
    {
        int cmb = wid*16 + quad*4;
        f32x4 s = *(const f32x4*)&bnp[256 + cmb];
        f32x4 tt = *(const f32x4*)&bnp[320 + cmb];
        u16x4 pk;
        #pragma unroll
        for (int r = 0; r < 4; r++) {
            bf16 v = (bf16)fmaxf(acc3[r]*s[r] + tt[r], 0.f);
            pk[r] = *(U16*)&v;
        }
        int gv = ((wid*2 + (quad >> 1)) + col) & 7;
        *(u16x4*)&v3t[col*64 + gv*8 + (quad & 1)*4] = pk;
    }
    __syncthreads();

    // ---- phase C3: stage 4 (M=144 over waves 3/2/2/2) -> fp32 out ----
    for (int mt4 = wid; mt4 < 9; mt4 += 4) {
        f32x4 acc4 = {};
        #pragma unroll
        for (int ks4 = 0; ks4 < 2; ks4++) {
            bf16x8 afr = *(const bf16x8*)(w_outf + ((mt4*2 + ks4)*64 + lane)*8);
            int gv = ((ks4*4 + quad) + col) & 7;
            bf16x8 bfr = *(const bf16x8*)&v3t[col*64 + gv*8];
            acc4 = MFMA(afr, bfr, acc4, 0, 0, 0);
        }
        #pragma unroll
        for (int r = 0; r < 4; r++) {
            int oc = mt4*16 + quad*4 + r;
            out[((size_t)(b*144 + oc))*4096 + hw0 + col] = acc4[r]*bnp[384 + oc] + bnp[528 + oc];
        }
    }
}

// ------------------------------------------------------------------
extern "C" void kernel_launch(void* const* d_in, const int* in_sizes, int n_in,
                              void* d_out, int out_size, void* d_ws, size_t ws_size,
                              hipStream_t stream)
{
    const float* x     = (const float*)d_in[0];
    const float* w_in  = (const float*)d_in[1];
    const float* g_in  = (const float*)d_in[2];
    const float* b_in  = (const float*)d_in[3];
    const float* m_in  = (const float*)d_in[4];
    const float* v_in  = (const float*)d_in[5];
    const float* w1    = (const float*)d_in[6];
    const float* g1    = (const float*)d_in[7];
    const float* b1    = (const float*)d_in[8];
    const float* m1    = (const float*)d_in[9];
    const float* v1    = (const float*)d_in[10];
    const float* w2    = (const float*)d_in[11];
    const float* g2    = (const float*)d_in[12];
    const float* b2    = (const float*)d_in[13];
    const float* m2    = (const float*)d_in[14];
    const float* v2    = (const float*)d_in[15];
    const float* w_out = (const float*)d_in[16];
    const float* g_out = (const float*)d_in[17];
    const float* b_out = (const float*)d_in[18];
    const float* m_out = (const float*)d_in[19];
    const float* v_out = (const float*)d_in[20];
    float* out = (float*)d_out;

    char* ws = (char*)d_ws;
    bf16*  xn     = (bf16*)(ws + XN_OFF);
    bf16*  a1     = (bf16*)(ws + A1_OFF);
    bf16*  w_inf  = (bf16*)(ws + WINF_OFF);
    bf16*  w1f    = (bf16*)(ws + W1F_OFF);
    bf16*  w2f    = (bf16*)(ws + W2F_OFF);
    bf16*  w_outf = (bf16*)(ws + WOUTF_OFF);
    float* bnp    = (float*)(ws + BNP_OFF);

    hipLaunchKernelGGL(k_norm, dim3(256), dim3(256), 0, stream, x, xn);
    hipLaunchKernelGGL(k_pack, dim3(367), dim3(256), 0, stream,
                       w_in, w1, w2, w_out,
                       g_in, b_in, m_in, v_in, g1, b1, m1, v1,
                       g2, b2, m2, v2, g_out, b_out, m_out, v_out,
                       w_inf, w1f, w2f, w_outf, bnp);
    hipLaunchKernelGGL(k_s1, dim3(1280), dim3(256), 0, stream, xn, w_inf, bnp, a1);
    hipLaunchKernelGGL(k_s234, dim3(1024), dim3(256), 0, stream,
                       a1, w1f, w2f, w_outf, bnp, out);
}

// Round 11
// 165.348 us; speedup vs baseline: 1.2899x; 1.0639x over previous
//
#include <hip/hip_runtime.h>

// Problem constants
#define BB   4
#define CC   144
#define HW   4096      // 64*64
#define PTOT 16384     // BB*HW
#define EPSB 1e-5f

typedef __bf16 bf16;
typedef __bf16 bf16x8 __attribute__((ext_vector_type(8)));
typedef float  f32x4  __attribute__((ext_vector_type(4)));
typedef unsigned short U16;
typedef unsigned int   U32;
typedef U16 u16x4 __attribute__((ext_vector_type(4)));
typedef U16 u16x8 __attribute__((ext_vector_type(8)));

#define MFMA __builtin_amdgcn_mfma_f32_16x16x32_bf16

// ---- workspace layout (bytes) ----
#define XN_OFF    0UL         // bf16 [16384][144] channel-last   4,718,592
#define A1_OFF    4718592UL   // bf16 [16384][25][64]             52,428,800
#define A2_OFF    57147392UL  // bf16 [16384][9][64] (k=rs*64+c2) 18,874,368
#define WINF_OFF  76021760UL  // bf16 frag [4][5][64][8]          20,480
#define W1F_OFF   76042240UL  // bf16 frag [4][18][64][8]         73,728
#define W2F_OFF   76115968UL  // bf16 frag [4][18][64][8]         73,728
#define WOUTF_OFF 76189696UL  // bf16 frag [9][2][64][8]          18,432
#define BNP_OFF   76208128UL  // f32 [672]

// ------------------------------------------------------------------
// K1: L2 normalize over channel dim -> xn channel-last [p][144] bf16
__global__ __launch_bounds__(256) void k_norm(const float* __restrict__ x,
                                              bf16* __restrict__ xn)
{
    __shared__ float red[4][64];
    int bh = blockIdx.x;
    int b = bh >> 6, h = bh & 63;
    int t = threadIdx.x, w = t & 63, cq = t >> 6;
    const float* px = x + ((size_t)b*CC)*HW + h*64 + w;
    float vals[36];
    float s = 0.f;
    #pragma unroll
    for (int i = 0; i < 36; i++) { float v = px[(size_t)(cq*36 + i)*HW]; vals[i] = v; s += v*v; }
    red[cq][w] = s;
    __syncthreads();
    float tot = red[0][w] + red[1][w] + red[2][w] + red[3][w];
    float inv = 1.f / fmaxf(sqrtf(tot), 1e-12f);
    U16* po = (U16*)(xn + ((size_t)(bh*64 + w))*144 + cq*36);
    #pragma unroll
    for (int k = 0; k < 9; k++) {
        u16x4 pk;
        #pragma unroll
        for (int r = 0; r < 4; r++) { bf16 v = (bf16)(vals[k*4+r]*inv); pk[r] = *(U16*)&v; }
        *(u16x4*)(po + k*4) = pk;
    }
}

// ------------------------------------------------------------------
// K2: pack weights into MFMA A-fragment order + fold BN params
__global__ __launch_bounds__(256) void k_pack(
    const float* __restrict__ w_in, const float* __restrict__ w1,
    const float* __restrict__ w2,   const float* __restrict__ w_out,
    const float* g_in, const float* b_in, const float* m_in, const float* v_in,
    const float* g1,   const float* b1,   const float* m1,   const float* v1,
    const float* g2,   const float* b2,   const float* m2,   const float* v2,
    const float* g_out,const float* b_out,const float* m_out,const float* v_out,
    bf16* w_inf, bf16* w1f, bf16* w2f, bf16* w_outf, float* bnp)
{
    int t = blockIdx.x*256 + threadIdx.x;
    if (t < 10240) {                       // w_inf: k = c, padded 144->160
        int e = t, j = e & 7, lane = (e >> 3) & 63, r = e >> 9;
        int ks = r % 5, mt = r / 5;
        int o = mt*16 + (lane & 15);
        int c = ks*32 + ((lane >> 4) << 3) + j;
        w_inf[e] = (c < 144) ? (bf16)w_in[o*144 + c] : (bf16)0.f;
    } else if (t < 47104) {                // w1f: K=576, k = ij*64 + c
        int e = t - 10240, j = e & 7, lane = (e >> 3) & 63, r = e >> 9;
        int ks = r % 18, mt = r / 18;
        int o = mt*16 + (lane & 15);
        int k = ks*32 + ((lane >> 4) << 3) + j;
        int ij = k >> 6, c = k & 63;
        w1f[e] = (bf16)w1[(o*64 + c)*9 + ij];
    } else if (t < 83968) {                // w2f: k = rs*64 + c2
        int e = t - 47104, j = e & 7, lane = (e >> 3) & 63, r = e >> 9;
        int ks = r % 18, mt = r / 18;
        int o = mt*16 + (lane & 15);
        int k = ks*32 + ((lane >> 4) << 3) + j;
        int rs = k >> 6, c2 = k & 63;
        w2f[e] = (bf16)w2[o*576 + c2*9 + rs];
    } else if (t < 93184) {                // w_outf: M=144 (9 mt), K=64 (2 ks)
        int e = t - 83968, j = e & 7, lane = (e >> 3) & 63, r = e >> 9;
        int ks = r & 1, mt = r >> 1;
        int o = mt*16 + (lane & 15);
        int c = ks*32 + ((lane >> 4) << 3) + j;
        w_outf[e] = (bf16)w_out[o*64 + c];
    } else if (t < 93856) {                // BN fold
        int i = t - 93184;
        const float *g, *bb, *mm, *vv; int c; bool is_t;
        if (i < 128)      { g=g_in; bb=b_in; mm=m_in; vv=v_in; c=i&63;        is_t=i>=64;  }
        else if (i < 256) { g=g1;   bb=b1;   mm=m1;   vv=v1;   c=(i-128)&63;  is_t=i>=192; }
        else if (i < 384) { g=g2;   bb=b2;   mm=m2;   vv=v2;   c=(i-256)&63;  is_t=i>=320; }
        else              { int ii=i-384; g=g_out; bb=b_out; mm=m_out; vv=v_out;
                            c = ii % 144; is_t = ii >= 144; }
        float s = g[c] * rsqrtf(vv[c] + EPSB);
        bnp[i] = is_t ? (bb[c] - mm[c]*s) : s;
    }
}

// ------------------------------------------------------------------
// K3: stage 1 (R6 proven). Block = one image row x one dh (kpg).
#define LROW 168
__global__ __launch_bounds__(256) void k_s1(const bf16* __restrict__ xn,
        const bf16* __restrict__ w_inf, const float* __restrict__ bnp,
        bf16* __restrict__ a1)
{
    __shared__ __align__(16) U16 nb[68*LROW];   // 22848 B
    int t = threadIdx.x;
    int wid = t >> 6, lane = t & 63, quad = lane >> 4, col16 = lane & 15;
    int tile = blockIdx.x & 255, kpg = blockIdx.x >> 8;
    int dh = kpg - 2;
    int h = tile & 63;
    int p = tile*64 + wid*16 + col16;
    int w = p & 63;
    const bf16* xrow = xn + (size_t)p*144;

    int hr = h + dh;
    u16x8 z = {};
    if ((unsigned)hr < 64u) {
        for (int i = t; i < 84; i += 256) {
            int r = i / 21, cc = i % 21;
            int row = (r < 2) ? r : 64 + r;
            *(u16x8*)&nb[row*LROW + cc*8] = z;
        }
        for (int i = t; i < 192; i += 256) {
            int row = 2 + i / 3, cc = 18 + (i % 3);
            *(u16x8*)&nb[row*LROW + cc*8] = z;
        }
        const U16* grow = (const U16*)(xn + ((size_t)(tile + dh) * 64) * 144);
        for (int i = t; i < 1152; i += 256) {
            int wcol = i / 18, k16 = i - 18*wcol;
            u16x8 v = *(const u16x8*)(grow + wcol*144 + k16*8);
            *(u16x8*)&nb[(2 + wcol)*LROW + k16*8] = v;
        }
    } else {
        for (int i = t; i < 68*LROW/8; i += 256) *(u16x8*)&nb[i*8] = z;
    }
    bf16x8 af[4][5];
    #pragma unroll
    for (int mt = 0; mt < 4; mt++)
        #pragma unroll
        for (int ks = 0; ks < 5; ks++)
            af[mt][ks] = *(const bf16x8*)(w_inf + ((mt*5 + ks)*64 + lane)*8);
    bf16x8 cfr[5];
    #pragma unroll
    for (int ks = 0; ks < 5; ks++) {
        bf16x8 zz = {};
        cfr[ks] = (ks < 4 || quad < 2) ? *(const bf16x8*)(xrow + ks*32 + quad*8) : zz;
    }
    f32x4 sv[4], tv[4];
    #pragma unroll
    for (int mt = 0; mt < 4; mt++) {
        sv[mt] = *(const f32x4*)&bnp[mt*16 + quad*4];
        tv[mt] = *(const f32x4*)&bnp[64 + mt*16 + quad*4];
    }
    __syncthreads();

    for (int kpl = 0; kpl < 5; kpl++) {
        const bf16* lrow = (const bf16*)&nb[(w + kpl)*LROW];
        f32x4 acc[4] = {};
        #pragma unroll
        for (int ks = 0; ks < 5; ks++) {
            bf16x8 nv = *(const bf16x8*)(lrow + ks*32 + quad*8);
            bf16x8 bfr;
            #pragma unroll
            for (int j = 0; j < 8; j++)
                bfr[j] = (bf16)((float)nv[j] * (float)cfr[ks][j]);
            #pragma unroll
            for (int mt = 0; mt < 4; mt++)
                acc[mt] = MFMA(af[mt][ks], bfr, acc[mt], 0, 0, 0);
        }
        int kp = kpg*5 + kpl;
        bf16* arow = a1 + (size_t)p*1600 + kp*64;
        #pragma unroll
        for (int mt = 0; mt < 4; mt++) {
            u16x4 pk;
            #pragma unroll
            for (int r = 0; r < 4; r++) {
                bf16 v = (bf16)fmaxf(acc[mt][r]*sv[mt][r] + tv[mt][r], 0.f);
                pk[r] = *(U16*)&v;
            }
            *(u16x4*)(arow + mt*16 + quad*4) = pk;
        }
    }
}

// ------------------------------------------------------------------
// K4: stage 2 GEMM (R6 structure). Block stages 16 a1 rows into LDS with
// PADDED stride 1608 els (3216 B = 4 dwords mod 32 banks -> 2-way = free),
// no XOR swizzle math in the inner loop. Wave = 2mt x 4nt. grid 1152.
#define PSTR 1608
__global__ __launch_bounds__(256) void k_s2(const bf16* __restrict__ w1f,
        const bf16* __restrict__ a1, const float* __restrict__ bnp,
        bf16* __restrict__ a2)
{
    __shared__ __align__(16) U16 Bs[16*PSTR];   // 51456 B
    int t = threadIdx.x;
    int wid = t >> 6, lane = t & 63, quad = lane >> 4, col16 = lane & 15;
    int nhalf = wid >> 1, mhalf = wid & 1;
    const int LUT5[9] = {0,1,2,5,6,7,10,11,12};
    int bid = blockIdx.x;
    bid = (bid & 7)*144 + (bid >> 3);      // XCD swizzle
    int n0 = bid*128;
    int pf = n0 / 9;

    // ---- stage 16 a1 rows -> LDS (coalesced, deep queue, padded stride) ----
    const U16* gsrc = (const U16*)(a1 + (size_t)pf*1600);
    u16x8 sreg[13];
    #pragma unroll
    for (int it = 0; it < 13; it++) {
        int i = it*256 + t;
        if (i < 3200) sreg[it] = *(const u16x8*)(gsrc + i*8);
    }
    #pragma unroll
    for (int it = 0; it < 13; it++) {
        int i = it*256 + t;
        if (i < 3200) {
            int grp = i & 7, rem = i >> 3;
            int kpidx = rem % 25, prow = rem / 25;
            *(u16x8*)&Bs[prow*PSTR + kpidx*64 + grp*8] = sreg[it];
        }
    }

    int pd4[4], lrs[4]; U32 oN[4];
    #pragma unroll
    for (int nt = 0; nt < 4; nt++) {
        int n = n0 + nhalf*64 + nt*16 + col16;
        int pp = n / 9, rs = n - 9*pp;
        pd4[nt] = (pp - pf)*PSTR; lrs[nt] = LUT5[rs];
        oN[nt] = (U32)pp*576 + (U32)rs*64;
    }
    bf16x8 aa[2][2];
    #pragma unroll
    for (int m = 0; m < 2; m++)
        aa[0][m] = *(const bf16x8*)(w1f + (((mhalf*2 + m)*18)*64 + lane)*8);
    __syncthreads();

    f32x4 acc[2][4] = {};
    #pragma unroll
    for (int ks = 0; ks < 18; ks++) {
        int ij = ks >> 1, goff = (ks & 1)*32 + quad*8;
        if (ks + 1 < 18) {                 // A ring-2 / lookahead-1
            #pragma unroll
            for (int m = 0; m < 2; m++)
                aa[(ks+1) & 1][m] = *(const bf16x8*)(w1f + (((mhalf*2 + m)*18 + ks + 1)*64 + lane)*8);
        }
        bf16x8 bfr[4];
        #pragma unroll
        for (int nt = 0; nt < 4; nt++) {
            int kpidx = LUT5[ij] + lrs[nt];
            bfr[nt] = *(const bf16x8*)&Bs[pd4[nt] + kpidx*64 + goff];
        }
        #pragma unroll
        for (int m = 0; m < 2; m++)
            #pragma unroll
            for (int nt = 0; nt < 4; nt++)
                acc[m][nt] = MFMA(aa[ks & 1][m], bfr[nt], acc[m][nt], 0, 0, 0);
    }
    // epilogue: BN + ReLU -> a2[p][rs][c2] (contiguous u16x4 stores)
    #pragma unroll
    for (int m = 0; m < 2; m++) {
        int ob = (mhalf*2 + m)*16 + quad*4;
        f32x4 s = *(const f32x4*)&bnp[128 + ob];
        f32x4 tt = *(const f32x4*)&bnp[192 + ob];
        #pragma unroll
        for (int nt = 0; nt < 4; nt++) {
            u16x4 pk;
            #pragma unroll
            for (int r = 0; r < 4; r++) {
                bf16 v = (bf16)fmaxf(acc[m][nt][r]*s[r] + tt[r], 0.f);
                pk[r] = *(U16*)&v;
            }
            *(u16x4*)(a2 + oN[nt] + ob) = pk;
        }
    }
}

// ------------------------------------------------------------------
// K5: stage 3 (64x576, 32 cols/block; a2 chunk staged to LDS, padded
// stride 584) + BN/ReLU -> v3 (stride 72) -> stage 4 (144x64) -> fp32 out.
#define APITCH 584
#define VPITCH 72
__global__ __launch_bounds__(256) void k_s34(const bf16* __restrict__ a2,
        const bf16* __restrict__ w2f, const bf16* __restrict__ w_outf,
        const float* __restrict__ bnp, float* __restrict__ out)
{
    __shared__ __align__(16) U16 As[32*APITCH];  // 37376 B
    __shared__ __align__(16) U16 v3[32*VPITCH];  // 4608 B
    int t = threadIdx.x, wid = t >> 6, lane = t & 63, quad = lane >> 4, col16 = lane & 15;
    int p0 = blockIdx.x * 32;
    int b = p0 >> 12, hw0 = p0 & 4095;

    const U16* gsrc = (const U16*)(a2 + (size_t)p0*576);
    u16x8 sreg[9];
    #pragma unroll
    for (int it = 0; it < 9; it++) sreg[it] = *(const u16x8*)(gsrc + (it*256 + t)*8);
    #pragma unroll
    for (int it = 0; it < 9; it++) {
        int i = it*256 + t;
        int c = i % 72, pr = i / 72;
        *(u16x8*)&As[pr*APITCH + c*8] = sreg[it];
    }
    bf16x8 aa[2];
    aa[0] = *(const bf16x8*)(w2f + ((wid*18)*64 + lane)*8);
    __syncthreads();

    f32x4 acc[2] = {};
    #pragma unroll
    for (int ks = 0; ks < 18; ks++) {
        if (ks + 1 < 18)
            aa[(ks+1) & 1] = *(const bf16x8*)(w2f + ((wid*18 + ks + 1)*64 + lane)*8);
        int goff = (ks*4 + quad)*8;
        #pragma unroll
        for (int nt = 0; nt < 2; nt++) {
            int p = nt*16 + col16;
            bf16x8 bfr = *(const bf16x8*)&As[p*APITCH + goff];
            acc[nt] = MFMA(aa[ks & 1], bfr, acc[nt], 0, 0, 0);
        }
    }
    #pragma unroll
    for (int nt = 0; nt < 2; nt++) {
        int colA = nt*16 + col16;
        int o0 = wid*16 + quad*4;
        f32x4 s = *(const f32x4*)&bnp[256 + o0];
        f32x4 tt = *(const f32x4*)&bnp[320 + o0];
        u16x4 pk;
        #pragma unroll
        for (int r = 0; r < 4; r++) {
            bf16 yb = (bf16)fmaxf(acc[nt][r]*s[r] + tt[r], 0.f);
            pk[r] = *(U16*)&yb;
        }
        *(u16x4*)&v3[colA*VPITCH + o0] = pk;
    }
    __syncthreads();
    for (int mt = wid; mt < 9; mt += 4) {
        f32x4 accB[2] = {};
        #pragma unroll
        for (int ks = 0; ks < 2; ks++) {
            bf16x8 afr = *(const bf16x8*)(w_outf + ((mt*2 + ks)*64 + lane)*8);
            #pragma unroll
            for (int nt = 0; nt < 2; nt++) {
                int colA = nt*16 + col16;
                bf16x8 bfr = *(const bf16x8*)&v3[colA*VPITCH + ks*32 + quad*8];
                accB[nt] = MFMA(afr, bfr, accB[nt], 0, 0, 0);
            }
        }
        #pragma unroll
        for (int nt = 0; nt < 2; nt++) {
            #pragma unroll
            for (int r = 0; r < 4; r++) {
                int oc = mt*16 + quad*4 + r;
                float s = bnp[384 + oc], tt = bnp[528 + oc];
                out[((size_t)(b*144 + oc))*4096 + hw0 + nt*16 + col16] = accB[nt][r]*s + tt;
            }
        }
    }
}

// ------------------------------------------------------------------
extern "C" void kernel_launch(void* const* d_in, const int* in_sizes, int n_in,
                              void* d_out, int out_size, void* d_ws, size_t ws_size,
                              hipStream_t stream)
{
    const float* x     = (const float*)d_in[0];
    const float* w_in  = (const float*)d_in[1];
    const float* g_in  = (const float*)d_in[2];
    const float* b_in  = (const float*)d_in[3];
    const float* m_in  = (const float*)d_in[4];
    const float* v_in  = (const float*)d_in[5];
    const float* w1    = (const float*)d_in[6];
    const float* g1    = (const float*)d_in[7];
    const float* b1    = (const float*)d_in[8];
    const float* m1    = (const float*)d_in[9];
    const float* v1    = (const float*)d_in[10];
    const float* w2    = (const float*)d_in[11];
    const float* g2    = (const float*)d_in[12];
    const float* b2    = (const float*)d_in[13];
    const float* m2    = (const float*)d_in[14];
    const float* v2    = (const float*)d_in[15];
    const float* w_out = (const float*)d_in[16];
    const float* g_out = (const float*)d_in[17];
    const float* b_out = (const float*)d_in[18];
    const float* m_out = (const float*)d_in[19];
    const float* v_out = (const float*)d_in[20];
    float* out = (float*)d_out;

    char* ws = (char*)d_ws;
    bf16*  xn     = (bf16*)(ws + XN_OFF);
    bf16*  a1     = (bf16*)(ws + A1_OFF);
    bf16*  a2     = (bf16*)(ws + A2_OFF);
    bf16*  w_inf  = (bf16*)(ws + WINF_OFF);
    bf16*  w1f    = (bf16*)(ws + W1F_OFF);
    bf16*  w2f    = (bf16*)(ws + W2F_OFF);
    bf16*  w_outf = (bf16*)(ws + WOUTF_OFF);
    float* bnp    = (float*)(ws + BNP_OFF);

    hipLaunchKernelGGL(k_norm, dim3(256), dim3(256), 0, stream, x, xn);
    hipLaunchKernelGGL(k_pack, dim3(367), dim3(256), 0, stream,
                       w_in, w1, w2, w_out,
                       g_in, b_in, m_in, v_in, g1, b1, m1, v1,
                       g2, b2, m2, v2, g_out, b_out, m_out, v_out,
                       w_inf, w1f, w2f, w_outf, bnp);
    hipLaunchKernelGGL(k_s1, dim3(1280), dim3(256), 0, stream, xn, w_inf, bnp, a1);
    hipLaunchKernelGGL(k_s2, dim3(1152), dim3(256), 0, stream, w1f, a1, bnp, a2);
    hipLaunchKernelGGL(k_s34, dim3(512), dim3(256), 0, stream, a2, w2f, w_outf, bnp, out);
}